// Round 5
// baseline (238.585 us; speedup 1.0000x reference)
//
#include <hip/hip_runtime.h>

#define N_RES   2000000
#define HIDDEN  128
#define BLK     256
#define NTILES  7813     // ceil(N_RES / BLK); last tile has 128 residues
#define GRID    2048     // ~8 blocks/CU; grid-stride over tiles (Guideline 11)

// ---------------------------------------------------------------------------
// Kernel A: the tiny MLP + frame transform (one block; runs in a few µs).
//   fl (2,53) = concat(features(2,50), latent.reshape(2,3))
//   h  = relu(fl @ W1 + b1)          (2,128)
//   s  = h @ W2 + b2                 (2,3)
//   tv = s @ local_frame^T           (2,3)  -> d_ws
// ---------------------------------------------------------------------------
__global__ void mlp_kernel(const float* __restrict__ latent,    // 6
                           const float* __restrict__ features,  // 2*50
                           const float* __restrict__ W1,        // 53*128
                           const float* __restrict__ b1,        // 128
                           const float* __restrict__ W2,        // 128*3
                           const float* __restrict__ b2,        // 3
                           const float* __restrict__ lf,        // 3*3
                           float* __restrict__ tv_out)          // 6
{
    __shared__ float h[2][HIDDEN];
    __shared__ float s[2][3];
    const int tid = threadIdx.x;
    const int d = tid >> 7;          // 0..1
    const int j = tid & 127;         // 0..127

    float acc = b1[j];
    #pragma unroll 10
    for (int k = 0; k < 50; ++k)
        acc += features[d * 50 + k] * W1[k * HIDDEN + j];
    #pragma unroll
    for (int k = 0; k < 3; ++k)
        acc += latent[d * 3 + k] * W1[(50 + k) * HIDDEN + j];
    h[d][j] = fmaxf(acc, 0.0f);
    __syncthreads();

    if (tid < 6) {
        const int dd = tid / 3, c = tid % 3;
        float a = b2[c];
        #pragma unroll 16
        for (int k = 0; k < HIDDEN; ++k)
            a += h[dd][k] * W2[k * 3 + c];
        s[dd][c] = a;
    }
    __syncthreads();

    if (tid < 6) {
        const int dd = tid / 3, c = tid % 3;
        // tv[dd][c] = sum_k s[dd][k] * lf[c][k]   (note: @ lf^T)
        float a = 0.0f;
        #pragma unroll
        for (int k = 0; k < 3; ++k)
            a += s[dd][k] * lf[c * 3 + k];
        tv_out[dd * 3 + c] = a;
    }
}

// ---------------------------------------------------------------------------
// Kernel B: streaming deform, grid-stride over 256-residue tiles.
//  - 2048 WGs total (vs 7813): per-WG launch/drain cost amortized 4x; blocks
//    stay resident and occupancy stays high through the whole kernel.
//  - body identical to round-4 version; LDS double-buffered so ONE
//    __syncthreads per tile (barrier of tile i+1 orders tile-i reads before
//    tile-i+2 writes to the same buffer).
// ---------------------------------------------------------------------------
__global__ __launch_bounds__(BLK) void deform_kernel(
    const float* __restrict__ weights,   // (nbw, 2)
    const float* __restrict__ pos,       // (6M, 3)
    const float* __restrict__ tv,        // (2, 3) in d_ws
    float* __restrict__ out_pos,         // 18M
    float* __restrict__ out_attn,        // 4M
    float* __restrict__ out_trans)       // 6M
{
    __shared__ __align__(16) float t_lds[2][3 * BLK];

    const int tid = threadIdx.x;
    // tv: 6 uniform floats, L2-resident broadcast loads.
    const float tv0 = tv[0], tv1 = tv[1], tv2 = tv[2];
    const float tv3 = tv[3], tv4 = tv[4], tv5 = tv[5];

    int buf = 0;
    for (int tile = blockIdx.x; tile < NTILES; tile += GRID, buf ^= 1) {
        const int r0   = tile * BLK;
        const int r    = r0 + tid;
        const int nres = min(BLK, N_RES - r0);   // 256, last tile 128
        const int nch  = (9 * nres) >> 2;        // 576, last tile 288

        // ---- streaming pos loads first (float4, fully coalesced) ----------
        const float4* __restrict__ pos4 = (const float4*)(pos + 9ll * r0);
        float4 pA = make_float4(0.f, 0.f, 0.f, 0.f);
        float4 pB = pA, pC = pA;
        if (tid            < nch) pA = pos4[tid];
        if (tid +     BLK  < nch) pB = pos4[tid + BLK];
        if (tid + 2 * BLK  < nch) pC = pos4[tid + 2 * BLK];

        // ---- per-residue attn + translation -------------------------------
        float t0 = 0.f, t1 = 0.f, t2 = 0.f;
        if (r < N_RES) {
            // closed-form window indices: start = ceil(max(r-9,0)/10)
            const int raw   = max(r - 9, 0);
            const int start = (raw + 9) / 10;
            const float2* wbase = (const float2*)(weights) + start;
            float p0 = 1.0f, p1 = 1.0f;
            #pragma unroll
            for (int j = 0; j < 10; ++j) {
                const float2 w = wbase[j];
                p0 *= w.x;
                p1 *= w.y;
            }
            const float m   = fmaxf(p0, p1);
            const float e0  = __expf(p0 - m);
            const float e1  = __expf(p1 - m);
            const float inv = 1.0f / (e0 + e1);
            const float a0  = e0 * inv;
            const float a1  = e1 * inv;

            ((float2*)out_attn)[r] = make_float2(a0, a1);  // 8B/lane, coalesced

            t0 = a0 * tv0 + a1 * tv3;
            t1 = a0 * tv1 + a1 * tv4;
            t2 = a0 * tv2 + a1 * tv5;
        }
        float* __restrict__ tl = t_lds[buf];
        tl[3 * tid + 0] = t0;     // stride-3: 2-way bank alias (free)
        tl[3 * tid + 1] = t1;
        tl[3 * tid + 2] = t2;
        __syncthreads();

        // ---- coalesced float4 epilogue ------------------------------------
        // out_trans: 3*nres floats, base 3072B*tile -> 16B aligned.
        const int ntr = (3 * nres) >> 2;
        if (tid < ntr)
            ((float4*)(out_trans + 3ll * r0))[tid] = ((const float4*)tl)[tid];

        // out_pos = pos + repeat(trans). One /9 per chunk, running (rl, cm).
        float4* __restrict__ o4 = (float4*)(out_pos + 9ll * r0);
        auto addt = [&](float4 v, int c) -> float4 {
            float* vp = (float*)&v;
            const int e = 4 * c;            // tile-local element, < 2304
            int rl = e / 9;                 // one magic-mul per chunk
            int cm = e - 9 * rl;            // 0..8
            #pragma unroll
            for (int k = 0; k < 4; ++k) {
                const int c3 = (cm >= 6) ? cm - 6 : ((cm >= 3) ? cm - 3 : cm);
                vp[k] += tl[3 * rl + c3];
                if (++cm == 9) { cm = 0; ++rl; }
            }
            return v;
        };
        if (tid            < nch) o4[tid          ] = addt(pA, tid          );
        if (tid +     BLK  < nch) o4[tid +     BLK] = addt(pB, tid +     BLK);
        if (tid + 2 * BLK  < nch) o4[tid + 2 * BLK] = addt(pC, tid + 2 * BLK);
    }
}

extern "C" void kernel_launch(void* const* d_in, const int* in_sizes, int n_in,
                              void* d_out, int out_size, void* d_ws, size_t ws_size,
                              hipStream_t stream) {
    const float* weights  = (const float*)d_in[0];
    const float* latent   = (const float*)d_in[1];
    const float* features = (const float*)d_in[2];
    const float* W1       = (const float*)d_in[3];
    const float* b1       = (const float*)d_in[4];
    const float* W2       = (const float*)d_in[5];
    const float* b2       = (const float*)d_in[6];
    const float* lf       = (const float*)d_in[7];
    const float* pos      = (const float*)d_in[8];
    // d_in[9] (bs_per_res) intentionally unread: indices recomputed in-kernel.

    float* out = (float*)d_out;
    float* tvw = (float*)d_ws;   // 6 floats of scratch

    mlp_kernel<<<1, 256, 0, stream>>>(latent, features, W1, b1, W2, b2, lf, tvw);

    deform_kernel<<<GRID, BLK, 0, stream>>>(
        weights, pos, tvw,
        out,                 // new_atom_positions: [0, 18M)
        out + 18000000,      // attn:               [18M, 22M)
        out + 22000000);     // translation:        [22M, 28M)
}

// Round 7
// 234.884 us; speedup vs baseline: 1.0158x; 1.0158x over previous
//
#include <hip/hip_runtime.h>

#define N_RES   2000000
#define HIDDEN  128
#define BLK     256
#define NTILES  7813     // ceil(N_RES / BLK); last tile has 128 residues
#define GRID    2048     // persistent blocks, ~8/CU; grid-stride over tiles

// clang-native vector types for __builtin_nontemporal_store
// (HIP float4/float2 are classes and are rejected by the builtin).
typedef float f32x4 __attribute__((ext_vector_type(4)));
typedef float f32x2 __attribute__((ext_vector_type(2)));

// ---------------------------------------------------------------------------
// Single fused persistent kernel.
//  - MLP prefix runs ONCE PER BLOCK (2048x, not 7813x like the failed round-1
//    fusion): ~55 MB of L2-resident W1 reads aggregate, fully overlapped,
//    then each block streams ~3.8 tiles of 256 residues.
//  - Outputs are write-once: non-temporal stores keep pos/weights L3-resident
//    (round-1 FETCH showed our writes evicting half of pos).
//  - LDS translation buffer double-buffered: ONE __syncthreads per tile.
// ---------------------------------------------------------------------------
__global__ __launch_bounds__(BLK) void fused_kernel(
    const float* __restrict__ weights,   // (nbw, 2)
    const float* __restrict__ latent,    // 6
    const float* __restrict__ features,  // 2*50
    const float* __restrict__ W1,        // 53*128
    const float* __restrict__ b1,        // 128
    const float* __restrict__ W2,        // 128*3
    const float* __restrict__ b2,        // 3
    const float* __restrict__ lf,        // 3*3
    const float* __restrict__ pos,       // (6M, 3)
    float* __restrict__ out_pos,         // 18M
    float* __restrict__ out_attn,        // 4M
    float* __restrict__ out_trans)       // 6M
{
    __shared__ float h[2][HIDDEN];
    __shared__ float sv[6];
    __shared__ float tvs[6];
    __shared__ __align__(16) float t_lds[2][3 * BLK];

    const int tid = threadIdx.x;

    // ---- once-per-block MLP prefix (amortized over ~3.8 tiles) ------------
    {
        const int d = tid >> 7, j = tid & 127;   // h[d][j]
        float acc = b1[j];
        #pragma unroll
        for (int k = 0; k < 50; ++k)
            acc += features[d * 50 + k] * W1[k * HIDDEN + j];
        #pragma unroll
        for (int k = 0; k < 3; ++k)
            acc += latent[d * 3 + k] * W1[(50 + k) * HIDDEN + j];
        h[d][j] = fmaxf(acc, 0.0f);
    }
    __syncthreads();
    {
        // s[dd][c] = b2[c] + sum_k h[dd][k] * W2[k*3+c]; 32-lane shfl reduce.
        const int dd   = tid >> 7;
        const int rest = tid & 127;
        const int c    = rest >> 5;              // 0..3 (c==3 idle)
        const int l    = rest & 31;
        if (c < 3) {
            float a = 0.f;
            #pragma unroll
            for (int m = 0; m < 4; ++m)
                a += h[dd][l + 32 * m] * W2[(l + 32 * m) * 3 + c];
            #pragma unroll
            for (int off = 16; off >= 1; off >>= 1)
                a += __shfl_xor(a, off, 64);     // stays within the 32-group
            if (l == 0) sv[dd * 3 + c] = a + b2[c];
        }
    }
    __syncthreads();
    if (tid < 6) {
        const int dd = tid / 3, c = tid % 3;
        // tv[dd][c] = sum_k s[dd][k] * lf[c][k]   (@ lf^T)
        float a = 0.f;
        #pragma unroll
        for (int k = 0; k < 3; ++k)
            a += sv[dd * 3 + k] * lf[c * 3 + k];
        tvs[tid] = a;
    }
    __syncthreads();

    const float tv0 = tvs[0], tv1 = tvs[1], tv2 = tvs[2];
    const float tv3 = tvs[3], tv4 = tvs[4], tv5 = tvs[5];

    // ---- grid-stride streaming loop ---------------------------------------
    int buf = 0;
    for (int tile = blockIdx.x; tile < NTILES; tile += GRID, buf ^= 1) {
        const int r0   = tile * BLK;
        const int r    = r0 + tid;
        const int nres = min(BLK, N_RES - r0);   // 256, last tile 128
        const int nch  = (9 * nres) >> 2;        // 576, last tile 288

        // pos float4 loads (fully coalesced, issued first)
        const float4* __restrict__ pos4 = (const float4*)(pos + 9ll * r0);
        float4 pA = make_float4(0.f, 0.f, 0.f, 0.f);
        float4 pB = pA, pC = pA;
        if (tid            < nch) pA = pos4[tid];
        if (tid +     BLK  < nch) pB = pos4[tid + BLK];
        if (tid + 2 * BLK  < nch) pC = pos4[tid + 2 * BLK];

        // per-residue attn + translation
        float t0 = 0.f, t1 = 0.f, t2 = 0.f;
        if (r < N_RES) {
            // closed-form window indices: start = ceil(max(r-9,0)/10)
            const int raw   = max(r - 9, 0);
            const int start = (raw + 9) / 10;
            const float2* wbase = (const float2*)(weights) + start;
            float p0 = 1.0f, p1 = 1.0f;
            #pragma unroll
            for (int j = 0; j < 10; ++j) {
                const float2 w = wbase[j];
                p0 *= w.x;
                p1 *= w.y;
            }
            const float m   = fmaxf(p0, p1);
            const float e0  = __expf(p0 - m);
            const float e1  = __expf(p1 - m);
            const float inv = 1.0f / (e0 + e1);
            const float a0  = e0 * inv;
            const float a1  = e1 * inv;

            f32x2 av; av.x = a0; av.y = a1;
            __builtin_nontemporal_store(av, (f32x2*)out_attn + r);

            t0 = a0 * tv0 + a1 * tv3;
            t1 = a0 * tv1 + a1 * tv4;
            t2 = a0 * tv2 + a1 * tv5;
        }
        float* __restrict__ tl = t_lds[buf];
        tl[3 * tid + 0] = t0;     // stride-3: 2-way bank alias (free)
        tl[3 * tid + 1] = t1;
        tl[3 * tid + 2] = t2;
        __syncthreads();

        // out_trans: 3*nres floats, base 3072B*tile -> 16B aligned.
        const int ntr = (3 * nres) >> 2;
        if (tid < ntr)
            __builtin_nontemporal_store(((const f32x4*)tl)[tid],
                                        (f32x4*)(out_trans + 3ll * r0) + tid);

        // out_pos = pos + repeat(trans). One /9 per chunk, running (rl, cm).
        f32x4* __restrict__ o4 = (f32x4*)(out_pos + 9ll * r0);
        auto addt = [&](float4 v, int c) -> f32x4 {
            float* vp = (float*)&v;
            const int e = 4 * c;            // tile-local element, < 2304
            int rl = e / 9;                 // one magic-mul per chunk
            int cm = e - 9 * rl;            // 0..8
            #pragma unroll
            for (int k = 0; k < 4; ++k) {
                const int c3 = (cm >= 6) ? cm - 6 : ((cm >= 3) ? cm - 3 : cm);
                vp[k] += tl[3 * rl + c3];
                if (++cm == 9) { cm = 0; ++rl; }
            }
            f32x4 rv; rv.x = v.x; rv.y = v.y; rv.z = v.z; rv.w = v.w;
            return rv;
        };
        if (tid            < nch)
            __builtin_nontemporal_store(addt(pA, tid          ), o4 + tid          );
        if (tid +     BLK  < nch)
            __builtin_nontemporal_store(addt(pB, tid +     BLK), o4 + tid +     BLK);
        if (tid + 2 * BLK  < nch)
            __builtin_nontemporal_store(addt(pC, tid + 2 * BLK), o4 + tid + 2 * BLK);
    }
}

extern "C" void kernel_launch(void* const* d_in, const int* in_sizes, int n_in,
                              void* d_out, int out_size, void* d_ws, size_t ws_size,
                              hipStream_t stream) {
    const float* weights  = (const float*)d_in[0];
    const float* latent   = (const float*)d_in[1];
    const float* features = (const float*)d_in[2];
    const float* W1       = (const float*)d_in[3];
    const float* b1       = (const float*)d_in[4];
    const float* W2       = (const float*)d_in[5];
    const float* b2       = (const float*)d_in[6];
    const float* lf       = (const float*)d_in[7];
    const float* pos      = (const float*)d_in[8];
    // d_in[9] (bs_per_res) intentionally unread: indices recomputed in-kernel.

    float* out = (float*)d_out;

    fused_kernel<<<GRID, BLK, 0, stream>>>(
        weights, latent, features, W1, b1, W2, b2, lf, pos,
        out,                 // new_atom_positions: [0, 18M)
        out + 18000000,      // attn:               [18M, 22M)
        out + 22000000);     // translation:        [22M, 28M)
}

// Round 8
// 232.879 us; speedup vs baseline: 1.0245x; 1.0086x over previous
//
#include <hip/hip_runtime.h>

#define N_RES   2000000
#define HIDDEN  128
#define BLK     256
#define GRID1   2048          // K1: persistent blocks, ~8/CU
#define NCH4    4500000       // K2: 18M out_pos floats / 4 per chunk

// clang-native vector type for __builtin_nontemporal_store
typedef float f32x4 __attribute__((ext_vector_type(4)));

// ---------------------------------------------------------------------------
// K1: attn + translation ONLY (no pos stream). Persistent grid; the tiny MLP
// runs once per block (amortized over ~3.8 residue batches, proven ~free in
// R7). Loop has NO barriers: each thread owns its residues end-to-end.
// trans/attn written with CACHED stores: K2 re-reads trans from L3.
// ---------------------------------------------------------------------------
__global__ __launch_bounds__(BLK) void attn_kernel(
    const float* __restrict__ weights,   // (nbw, 2)
    const float* __restrict__ latent,    // 6
    const float* __restrict__ features,  // 2*50
    const float* __restrict__ W1,        // 53*128
    const float* __restrict__ b1,        // 128
    const float* __restrict__ W2,        // 128*3
    const float* __restrict__ b2,        // 3
    const float* __restrict__ lf,        // 3*3
    float* __restrict__ out_attn,        // 4M
    float* __restrict__ out_trans)       // 6M
{
    __shared__ float h[2][HIDDEN];
    __shared__ float sv[6];
    __shared__ float tvs[6];

    const int tid = threadIdx.x;

    // ---- once-per-block MLP prefix ----------------------------------------
    {
        const int d = tid >> 7, j = tid & 127;   // h[d][j]
        float acc = b1[j];
        #pragma unroll
        for (int k = 0; k < 50; ++k)
            acc += features[d * 50 + k] * W1[k * HIDDEN + j];
        #pragma unroll
        for (int k = 0; k < 3; ++k)
            acc += latent[d * 3 + k] * W1[(50 + k) * HIDDEN + j];
        h[d][j] = fmaxf(acc, 0.0f);
    }
    __syncthreads();
    {
        // s[dd][c] = b2[c] + sum_k h[dd][k]*W2[k*3+c]; 32-lane shfl reduce.
        const int dd   = tid >> 7;
        const int rest = tid & 127;
        const int c    = rest >> 5;              // 0..3 (c==3 idle)
        const int l    = rest & 31;
        if (c < 3) {
            float a = 0.f;
            #pragma unroll
            for (int m = 0; m < 4; ++m)
                a += h[dd][l + 32 * m] * W2[(l + 32 * m) * 3 + c];
            #pragma unroll
            for (int off = 16; off >= 1; off >>= 1)
                a += __shfl_xor(a, off, 64);     // stays within the 32-group
            if (l == 0) sv[dd * 3 + c] = a + b2[c];
        }
    }
    __syncthreads();
    if (tid < 6) {
        const int dd = tid / 3, c = tid % 3;
        float a = 0.f;
        #pragma unroll
        for (int k = 0; k < 3; ++k)
            a += sv[dd * 3 + k] * lf[c * 3 + k];  // @ lf^T
        tvs[tid] = a;
    }
    __syncthreads();

    const float tv0 = tvs[0], tv1 = tvs[1], tv2 = tvs[2];
    const float tv3 = tvs[3], tv4 = tvs[4], tv5 = tvs[5];

    // ---- barrier-free residue loop ----------------------------------------
    for (int r = blockIdx.x * BLK + tid; r < N_RES; r += GRID1 * BLK) {
        // closed-form window indices: start = ceil(max(r-9,0)/10)
        const int raw   = max(r - 9, 0);
        const int start = (raw + 9) / 10;
        const float2* wbase = (const float2*)(weights) + start;
        float p0 = 1.0f, p1 = 1.0f;
        #pragma unroll
        for (int j = 0; j < 10; ++j) {
            const float2 w = wbase[j];
            p0 *= w.x;
            p1 *= w.y;
        }
        const float m   = fmaxf(p0, p1);
        const float e0  = __expf(p0 - m);
        const float e1  = __expf(p1 - m);
        const float inv = 1.0f / (e0 + e1);
        const float a0  = e0 * inv;
        const float a1  = e1 * inv;

        ((float2*)out_attn)[r] = make_float2(a0, a1);   // coalesced 8B/lane

        out_trans[3 * r + 0] = a0 * tv0 + a1 * tv3;     // cached: L3-hot for K2
        out_trans[3 * r + 1] = a0 * tv1 + a1 * tv4;
        out_trans[3 * r + 2] = a0 * tv2 + a1 * tv5;
    }
}

// ---------------------------------------------------------------------------
// K2: pure stream. out_pos4[j] = pos4[j] + gather4(trans). No window product,
// no softmax, no LDS, no barrier — the 144 MB HBM stream owns the waves.
// trans reads are L3-hits (24 MB, written by K1 moments ago; stream order
// guarantees visibility). NT stores keep the output from evicting trans.
// ---------------------------------------------------------------------------
__global__ __launch_bounds__(BLK) void stream_kernel(
    const float* __restrict__ pos,       // 18M floats
    const float* __restrict__ trans,     // 6M floats
    float* __restrict__ out_pos)         // 18M floats
{
    const int j = blockIdx.x * BLK + threadIdx.x;
    if (j >= NCH4) return;

    float4 v = ((const float4*)pos)[j];

    const int e = 4 * j;        // global element index, < 18M
    int rl = e / 9;             // residue (magic-mul)
    int cm = e - 9 * rl;        // 0..8
    float* vp = (float*)&v;
    #pragma unroll
    for (int k = 0; k < 4; ++k) {
        const int c3 = (cm >= 6) ? cm - 6 : ((cm >= 3) ? cm - 3 : cm);
        vp[k] += trans[3 * rl + c3];
        if (++cm == 9) { cm = 0; ++rl; }
    }

    f32x4 rv; rv.x = v.x; rv.y = v.y; rv.z = v.z; rv.w = v.w;
    __builtin_nontemporal_store(rv, (f32x4*)out_pos + j);
}

extern "C" void kernel_launch(void* const* d_in, const int* in_sizes, int n_in,
                              void* d_out, int out_size, void* d_ws, size_t ws_size,
                              hipStream_t stream) {
    const float* weights  = (const float*)d_in[0];
    const float* latent   = (const float*)d_in[1];
    const float* features = (const float*)d_in[2];
    const float* W1       = (const float*)d_in[3];
    const float* b1       = (const float*)d_in[4];
    const float* W2       = (const float*)d_in[5];
    const float* b2       = (const float*)d_in[6];
    const float* lf       = (const float*)d_in[7];
    const float* pos      = (const float*)d_in[8];
    // d_in[9] (bs_per_res) intentionally unread: indices recomputed in-kernel.

    float* out       = (float*)d_out;
    float* out_pos   = out;               // [0, 18M)
    float* out_attn  = out + 18000000;    // [18M, 22M)
    float* out_trans = out + 22000000;    // [22M, 28M)

    attn_kernel<<<GRID1, BLK, 0, stream>>>(
        weights, latent, features, W1, b1, W2, b2, lf,
        out_attn, out_trans);

    const int blocks = (NCH4 + BLK - 1) / BLK;   // 17579
    stream_kernel<<<blocks, BLK, 0, stream>>>(pos, out_trans, out_pos);
}